// Round 8
// baseline (222.613 us; speedup 1.0000x reference)
//
#include <hip/hip_runtime.h>
#include <hip/hip_bf16.h>
#include <stdint.h>

#define BS 4
#define NS 4096
#define NT 16384
#define CT 128
#define NOUT 256
#define MTOT (BS*NT) // 65536
#define GR 8
#define NC (GR*GR*GR)
#define HCELL 0.125f

typedef __attribute__((ext_vector_type(4))) float floatx4;
typedef __attribute__((ext_vector_type(8))) unsigned short ushortx8;
typedef __attribute__((ext_vector_type(8))) __bf16 bf16x8;

__device__ __forceinline__ unsigned short f2bf(float f) {
  unsigned int u = __builtin_bit_cast(unsigned int, f);
  u += 0x7FFFu + ((u >> 16) & 1u);
  return (unsigned short)(u >> 16);
}
__device__ __forceinline__ float bf2f(unsigned short u) {
  return __builtin_bit_cast(float, ((unsigned int)u) << 16);
}
__device__ __forceinline__ int cell_of(float x) {
  int c = (int)(x * 8.0f);
  return min(7, max(0, c));
}

// ---------------- prep: bucket sources (blk 0-3) + sort targets (blk 4-7) + weight transpose (blk 8+) ----------------
__global__ __launch_bounds__(1024) void prep_kernel(
    const float* __restrict__ xyzs, const float* __restrict__ xyzt,
    const float* __restrict__ w1, const float* __restrict__ w2,
    float4* __restrict__ bsrc, int* __restrict__ soff, float4* __restrict__ stgt,
    unsigned short* __restrict__ w1at, unsigned short* __restrict__ w1bt,
    unsigned short* __restrict__ w2t) {
  int bid = blockIdx.x, tid = threadIdx.x;
  if (bid < 8) {
    __shared__ int cnt[NC];
    __shared__ int scan[NC];
    int b = bid & 3;
    bool isrc = bid < 4;
    int per = isrc ? (NS >> 10) : (NT >> 10);
    const float* in = isrc ? xyzs + (size_t)b * NS * 3 : xyzt + (size_t)b * NT * 3;
    float4* outp = isrc ? bsrc + (size_t)b * NS : stgt + (size_t)b * NT;
    if (tid < NC) cnt[tid] = 0;
    __syncthreads();
    for (int k = 0; k < per; ++k) {
      int p = k * 1024 + tid;
      float x = in[3*p], y = in[3*p+1], z = in[3*p+2];
      int c = (cell_of(z) * GR + cell_of(y)) * GR + cell_of(x);
      atomicAdd(&cnt[c], 1);
    }
    __syncthreads();
    if (tid < NC) scan[tid] = cnt[tid];
    __syncthreads();
    for (int off = 1; off < NC; off <<= 1) {
      int v = (tid < NC && tid >= off) ? scan[tid - off] : 0;
      __syncthreads();
      if (tid < NC) scan[tid] += v;
      __syncthreads();
    }
    if (tid < NC) {
      int excl = scan[tid] - cnt[tid];
      cnt[tid] = excl;
      if (isrc) soff[b * (NC + 1) + tid] = excl;
    }
    if (isrc && tid == 0) soff[b * (NC + 1) + NC] = NS;
    __syncthreads();
    for (int k = 0; k < per; ++k) {
      int p = k * 1024 + tid;
      float x = in[3*p], y = in[3*p+1], z = in[3*p+2];
      int c = (cell_of(z) * GR + cell_of(y)) * GR + cell_of(x);
      int slot = atomicAdd(&cnt[c], 1);
      outp[slot] = make_float4(x, y, z, __int_as_float(p));
    }
  } else {
    int i = (bid - 8) * 1024 + tid;  // i < 65536
    int n = i >> 8, k = i & 255;
    w1at[i] = f2bf(w1[k * NOUT + n]);
    w2t[i]  = f2bf(w2[k * NOUT + n]);
    if (i < 256 * 128) {
      int n2 = i >> 7, k2 = i & 127;
      w1bt[i] = f2bf(w1[(256 + k2) * NOUT + n2]);
    }
  }
}

// ---------------- three_nn (bucketed, exact w/ clearance guard); outputs at SORTED positions ----------------
__device__ __forceinline__ void ins3(float sc, int jj,
    float& d0, float& d1, float& d2, int& i0, int& i1, int& i2) {
  bool l0 = sc < d0, l1 = sc < d1, l2 = sc < d2;
  d2 = l1 ? d1 : (l2 ? sc : d2);
  i2 = l1 ? i1 : (l2 ? jj : i2);
  d1 = l0 ? d0 : (l1 ? sc : d1);
  i1 = l0 ? i0 : (l1 ? jj : i1);
  d0 = l0 ? sc : d0;
  i0 = l0 ? jj : i0;
}

__device__ __forceinline__ void pair_merge(float& d0, float& d1, float& d2,
                                           int& i0, int& i1, int& i2,
                                           int delta, int sub) {
  float e0 = __shfl_xor(d0, delta);
  float e1 = __shfl_xor(d1, delta);
  float e2 = __shfl_xor(d2, delta);
  int   y0 = __shfl_xor(i0, delta);
  int   y1 = __shfl_xor(i1, delta);
  int   y2 = __shfl_xor(i2, delta);
  float a0,a1,a2,b0,b1,b2; int x0,x1,x2,z0,z1,z2;
  if ((sub & delta) == 0) { a0=d0;a1=d1;a2=d2; x0=i0;x1=i1;x2=i2;
                            b0=e0;b1=e1;b2=e2; z0=y0;z1=y1;z2=y2; }
  else                    { a0=e0;a1=e1;a2=e2; x0=y0;x1=y1;x2=y2;
                            b0=d0;b1=d1;b2=d2; z0=i0;z1=i1;z2=i2; }
  bool t = a0 <= b0;
  d0 = t ? a0 : b0; i0 = t ? x0 : z0;
  float na0 = t ? a1 : a0; int nx0 = t ? x1 : x0;
  float na1 = t ? a2 : a1; int nx1 = t ? x2 : x1;
  float nb0 = t ? b0 : b1; int nz0 = t ? z0 : z1;
  float nb1 = t ? b1 : b2; int nz1 = t ? z1 : z2;
  t = na0 <= nb0;
  d1 = t ? na0 : nb0; i1 = t ? nx0 : nz0;
  float ma0 = t ? na1 : na0; int mx0 = t ? nx1 : nx0;
  float mb0 = t ? nb0 : nb1; int mz0 = t ? nz0 : nz1;
  t = ma0 <= mb0;
  d2 = t ? ma0 : mb0; i2 = t ? mx0 : mz0;
}

// No LDS source staging: sorted targets make each block's candidate window
// ~8 KB of contiguous bsrc -> L1/L2-hot global reads; occupancy 2->4+ blocks/CU.
__global__ __launch_bounds__(256) void nn_kernel(const float4* __restrict__ stgt,
    const float4* __restrict__ bsrc, const int* __restrict__ soff,
    int* __restrict__ idx_out, float* __restrict__ w_out) {
  __shared__ int s_off[NC + 1];
  int tid = threadIdx.x;
  int b = blockIdx.x >> 7;
  int tseg = blockIdx.x & 127;
  const float4* srcb = bsrc + ((size_t)b << 12);
  for (int i = tid; i < NC + 1; i += 256) s_off[i] = soff[b * (NC + 1) + i];
  __syncthreads();
  int tpair = tid >> 1, half = tid & 1;
  float4 tg = stgt[(size_t)b * NT + tseg * 128 + tpair];
  float tx = tg.x, ty = tg.y, tz = tg.z;
  int cx = cell_of(tx), cy = cell_of(ty), cz = cell_of(tz);
  int wx = min(max(cx, 1), 6) - 1;
  int wy = min(max(cy, 1), 6) - 1;
  int wz = min(max(cz, 1), 6) - 1;
  float d0 = 1e30f, d1 = 1e30f, d2 = 1e30f;
  int i0 = 0, i1 = 0, i2 = 0;
  for (int r = half; r < 9; r += 2) {
    int ez = wz + r / 3, ey = wy + r % 3;
    int rowc = (ez * GR + ey) * GR + wx;
    int lo = s_off[rowc], hi = s_off[rowc + 3];
    for (int p = lo; p < hi; ++p) {
      float4 s = srcb[p];
      float dx = tx - s.x, dy = ty - s.y, dz = tz - s.z;
      float q = dx*dx + dy*dy + dz*dz;
      ins3(q, __float_as_int(s.w), d0, d1, d2, i0, i1, i2);
    }
  }
  pair_merge(d0, d1, d2, i0, i1, i2, 1, half);
  float clx = fminf(wx > 0 ? tx - wx * HCELL : 1e30f,
                    wx + 3 < GR ? (wx + 3) * HCELL - tx : 1e30f);
  float cly = fminf(wy > 0 ? ty - wy * HCELL : 1e30f,
                    wy + 3 < GR ? (wy + 3) * HCELL - ty : 1e30f);
  float clz = fminf(wz > 0 ? tz - wz * HCELL : 1e30f,
                    wz + 3 < GR ? (wz + 3) * HCELL - tz : 1e30f);
  float cl = fminf(clx, fminf(cly, clz));
  bool bad = d2 > cl * cl;
  if (__any(bad)) {
    if (bad) {
      d0 = d1 = d2 = 1e30f; i0 = i1 = i2 = 0;
      for (int p = half; p < NS; p += 2) {
        float4 s = srcb[p];
        float dx = tx - s.x, dy = ty - s.y, dz = tz - s.z;
        float q = dx*dx + dy*dy + dz*dz;
        ins3(q, __float_as_int(s.w), d0, d1, d2, i0, i1, i2);
      }
    }
    pair_merge(d0, d1, d2, i0, i1, i2, 1, half);
  }
  if (half == 0) {
    float r0 = fmaxf(sqrtf(d0), 1e-10f);
    float r1 = fmaxf(sqrtf(d1), 1e-10f);
    float r2 = fmaxf(sqrtf(d2), 1e-10f);
    float v0 = 1.f/r0, v1 = 1.f/r1, v2 = 1.f/r2;
    float sc = 1.f / ((v0 + v1 + v2) * (1.f + 1e-6f));
    size_t o = ((size_t)b * NT + tseg * 128 + tpair) * 3;
    idx_out[o] = i0; idx_out[o+1] = i1; idx_out[o+2] = i2;
    w_out[o] = v0*sc; w_out[o+1] = v1*sc; w_out[o+2] = v2*sc;
  }
}

// ---------------- G = fs @ W1a  (bf16 out, no relu) ----------------
__global__ __launch_bounds__(256) void gemm_g(const float* __restrict__ fs,
    const unsigned short* __restrict__ w1at, unsigned short* __restrict__ G) {
  constexpr int LDT = 72;
  __shared__ __attribute__((aligned(16))) unsigned short sA[128 * LDT];
  __shared__ __attribute__((aligned(16))) unsigned short sB[128 * LDT];
  int tid = threadIdx.x;
  int m0 = blockIdx.x * 128;
  int n0 = blockIdx.y * 128;
  int wave = tid >> 6, lane = tid & 63;
  int wm = (wave >> 1) * 64, wn = (wave & 1) * 64;
  int fr = lane & 15, quad = lane >> 4;
  floatx4 zero = {0.f, 0.f, 0.f, 0.f};
  floatx4 acc[4][4];
  #pragma unroll
  for (int i = 0; i < 4; ++i)
    #pragma unroll
    for (int j = 0; j < 4; ++j) acc[i][j] = zero;

  for (int kt = 0; kt < 256; kt += 64) {
    #pragma unroll
    for (int i = 0; i < 4; ++i) {
      int u = tid + 256 * i;
      int r = u >> 3, k8 = (u & 7) * 8;
      const float* src = fs + (size_t)(m0 + r) * 256 + kt + k8;
      float4 f0 = *(const float4*)src;
      float4 f1 = *(const float4*)(src + 4);
      ushortx8 o;
      o[0]=f2bf(f0.x); o[1]=f2bf(f0.y); o[2]=f2bf(f0.z); o[3]=f2bf(f0.w);
      o[4]=f2bf(f1.x); o[5]=f2bf(f1.y); o[6]=f2bf(f1.z); o[7]=f2bf(f1.w);
      *(ushortx8*)&sA[r * LDT + k8] = o;
    }
    #pragma unroll
    for (int i = 0; i < 4; ++i) {
      int u = tid + 256 * i;
      int n = u >> 3, kc = (u & 7) * 8;
      *(ushortx8*)&sB[n * LDT + kc] =
          *(const ushortx8*)(w1at + (size_t)(n0 + n) * 256 + kt + kc);
    }
    __syncthreads();
    #pragma unroll
    for (int kk = 0; kk < 64; kk += 32) {
      bf16x8 af[4], bfr[4];
      #pragma unroll
      for (int mi = 0; mi < 4; ++mi)
        af[mi] = __builtin_bit_cast(bf16x8,
            *(const ushortx8*)&sA[(wm + mi*16 + fr)*LDT + kk + quad*8]);
      #pragma unroll
      for (int ni = 0; ni < 4; ++ni)
        bfr[ni] = __builtin_bit_cast(bf16x8,
            *(const ushortx8*)&sB[(wn + ni*16 + fr)*LDT + kk + quad*8]);
      #pragma unroll
      for (int mi = 0; mi < 4; ++mi)
        #pragma unroll
        for (int ni = 0; ni < 4; ++ni)
          acc[mi][ni] = __builtin_amdgcn_mfma_f32_16x16x32_bf16(
              af[mi], bfr[ni], acc[mi][ni], 0, 0, 0);
    }
    __syncthreads();
  }
  #pragma unroll
  for (int mi = 0; mi < 4; ++mi)
    #pragma unroll
    for (int ni = 0; ni < 4; ++ni)
      #pragma unroll
      for (int r = 0; r < 4; ++r) {
        int grow = m0 + wm + mi*16 + quad*4 + r;
        int gcol = n0 + wn + ni*16 + fr;
        G[(size_t)grow * 256 + gcol] = f2bf(acc[mi][ni][r]);
      }
}

// ---------------- fused: out[orig] = relu(relu(interp + ft[orig]@W1b) @ W2) ----------------
// M=32 rows/block, 2048 blocks. LDS 25.6 KB; VGPR-bound 4 blocks/CU (16 waves).
__global__ __launch_bounds__(256, 4) void fused_mlp(const float* __restrict__ ft,
    const unsigned short* __restrict__ G, const int* __restrict__ idxb,
    const float* __restrict__ wgtb, const float4* __restrict__ stgt,
    const unsigned short* __restrict__ w1bt, const unsigned short* __restrict__ w2t,
    float* __restrict__ out) {
  constexpr int LDI = 264;
  constexpr int LDF = 136;
  __shared__ __attribute__((aligned(16))) unsigned short sI[32 * LDI];
  __shared__ __attribute__((aligned(16))) unsigned short sF[32 * LDF];
  int tid = threadIdx.x;
  int row0 = blockIdx.x * 32;   // global sorted row
  int b = row0 >> 14;
  const float4* st = stgt + ((size_t)b << 14) + (row0 & (NT - 1));
  const float* ftb = ft + (size_t)b * NT * CT;
  float* outb = out + (size_t)b * NT * NOUT;
  int wave = tid >> 6, lane = tid & 63;
  int wn = wave * 64;
  int fr = lane & 15, quad = lane >> 4;

  // ---- interp tile (32 rows x 256): thread = (r = tid>>3, seg = tid&7 -> 32 cols)
  {
    int r = tid >> 3, seg = tid & 7;
    const int* ip = idxb + (size_t)(row0 + r) * 3;
    const float* wp = wgtb + (size_t)(row0 + r) * 3;
    int g0i = ip[0], g1i = ip[1], g2i = ip[2];
    float w0 = wp[0], w1v = wp[1], w2v = wp[2];
    const unsigned short* Gb = G + ((size_t)b << 20);
    const unsigned short* g0 = Gb + ((size_t)g0i << 8) + seg * 32;
    const unsigned short* g1 = Gb + ((size_t)g1i << 8) + seg * 32;
    const unsigned short* g2 = Gb + ((size_t)g2i << 8) + seg * 32;
    #pragma unroll
    for (int j = 0; j < 4; ++j) {
      ushortx8 a = *(const ushortx8*)(g0 + j*8);
      ushortx8 c = *(const ushortx8*)(g1 + j*8);
      ushortx8 e = *(const ushortx8*)(g2 + j*8);
      ushortx8 o;
      #pragma unroll
      for (int q = 0; q < 8; ++q)
        o[q] = f2bf(w0*bf2f(a[q]) + w1v*bf2f(c[q]) + w2v*bf2f(e[q]));
      *(ushortx8*)&sI[r * LDI + seg * 32 + j * 8] = o;
    }
  }
  // ---- ft tile (32 x 128) fp32->bf16: 512 units of 8, 2/thread; rows gathered via orig
  #pragma unroll
  for (int i = 0; i < 2; ++i) {
    int u = tid + 256 * i;
    int r = u >> 4, k8 = (u & 15) * 8;
    int orig = __float_as_int(st[r].w);
    const float* src = ftb + (size_t)orig * CT + k8;
    float4 f0 = *(const float4*)src;
    float4 f1 = *(const float4*)(src + 4);
    ushortx8 o;
    o[0]=f2bf(f0.x); o[1]=f2bf(f0.y); o[2]=f2bf(f0.z); o[3]=f2bf(f0.w);
    o[4]=f2bf(f1.x); o[5]=f2bf(f1.y); o[6]=f2bf(f1.z); o[7]=f2bf(f1.w);
    *(ushortx8*)&sF[r * LDF + k8] = o;
  }
  __syncthreads();

  floatx4 zero = {0.f, 0.f, 0.f, 0.f};
  floatx4 acc[2][4];
  #pragma unroll
  for (int i = 0; i < 2; ++i)
    #pragma unroll
    for (int j = 0; j < 4; ++j) acc[i][j] = zero;

  // ---- phase 1: ft @ W1b (K=128), B-frags direct from global (L2-hot)
  #pragma unroll
  for (int kk = 0; kk < 128; kk += 32) {
    bf16x8 af[2], bfr[4];
    #pragma unroll
    for (int mi = 0; mi < 2; ++mi)
      af[mi] = __builtin_bit_cast(bf16x8,
          *(const ushortx8*)&sF[(mi*16 + fr)*LDF + kk + quad*8]);
    #pragma unroll
    for (int ni = 0; ni < 4; ++ni)
      bfr[ni] = __builtin_bit_cast(bf16x8,
          *(const ushortx8*)(w1bt + (size_t)(wn + ni*16 + fr) * CT + kk + quad*8));
    #pragma unroll
    for (int mi = 0; mi < 2; ++mi)
      #pragma unroll
      for (int ni = 0; ni < 4; ++ni)
        acc[mi][ni] = __builtin_amdgcn_mfma_f32_16x16x32_bf16(
            af[mi], bfr[ni], acc[mi][ni], 0, 0, 0);
  }

  // ---- phase-1 epilogue: T = relu(acc + interp) bf16, in-place in sI
  #pragma unroll
  for (int mi = 0; mi < 2; ++mi)
    #pragma unroll
    for (int ni = 0; ni < 4; ++ni)
      #pragma unroll
      for (int r = 0; r < 4; ++r) {
        int lr = mi*16 + quad*4 + r;
        int lc = wn + ni*16 + fr;
        float v = acc[mi][ni][r] + bf2f(sI[lr * LDI + lc]);
        sI[lr * LDI + lc] = f2bf(fmaxf(v, 0.f));
      }
  __syncthreads();

  // ---- phase 2: T @ W2 (K=256), no barriers
  #pragma unroll
  for (int i = 0; i < 2; ++i)
    #pragma unroll
    for (int j = 0; j < 4; ++j) acc[i][j] = zero;
  #pragma unroll
  for (int kk = 0; kk < 256; kk += 32) {
    bf16x8 af[2], bfr[4];
    #pragma unroll
    for (int mi = 0; mi < 2; ++mi)
      af[mi] = __builtin_bit_cast(bf16x8,
          *(const ushortx8*)&sI[(mi*16 + fr)*LDI + kk + quad*8]);
    #pragma unroll
    for (int ni = 0; ni < 4; ++ni)
      bfr[ni] = __builtin_bit_cast(bf16x8,
          *(const ushortx8*)(w2t + (size_t)(wn + ni*16 + fr) * NOUT + kk + quad*8));
    #pragma unroll
    for (int mi = 0; mi < 2; ++mi)
      #pragma unroll
      for (int ni = 0; ni < 4; ++ni)
        acc[mi][ni] = __builtin_amdgcn_mfma_f32_16x16x32_bf16(
            af[mi], bfr[ni], acc[mi][ni], 0, 0, 0);
  }
  // ---- out epilogue: scatter rows back to original positions
  #pragma unroll
  for (int mi = 0; mi < 2; ++mi)
    #pragma unroll
    for (int r = 0; r < 4; ++r) {
      int lr = mi*16 + quad*4 + r;
      int orig = __float_as_int(st[lr].w);
      float* orow = outb + (size_t)orig * NOUT;
      #pragma unroll
      for (int ni = 0; ni < 4; ++ni)
        orow[wn + ni*16 + fr] = fmaxf(acc[mi][ni][r], 0.f);
    }
}

extern "C" void kernel_launch(void* const* d_in, const int* in_sizes, int n_in,
                              void* d_out, int out_size, void* d_ws, size_t ws_size,
                              hipStream_t stream) {
  (void)in_sizes; (void)n_in; (void)out_size; (void)ws_size;
  const float* xyzt = (const float*)d_in[0];
  const float* xyzs = (const float*)d_in[1];
  const float* ft   = (const float*)d_in[2];
  const float* fs   = (const float*)d_in[3];
  const float* w1   = (const float*)d_in[4];
  const float* w2   = (const float*)d_in[5];

  char* p = (char*)d_ws;
  unsigned short* w1at = (unsigned short*)p; p += (size_t)256*256*2;
  unsigned short* w1bt = (unsigned short*)p; p += (size_t)256*128*2;
  unsigned short* w2t  = (unsigned short*)p; p += (size_t)256*256*2;
  int*   idxb = (int*)p;   p += (size_t)MTOT*3*4;
  float* wgtb = (float*)p; p += (size_t)MTOT*3*4;
  unsigned short* G = (unsigned short*)p; p += (size_t)BS*NS*NOUT*2;
  float4* bsrc = (float4*)p; p += (size_t)BS*NS*16;
  float4* stgt = (float4*)p; p += (size_t)BS*NT*16;
  int*    soff = (int*)p;

  hipLaunchKernelGGL(prep_kernel, dim3(8 + 64), dim3(1024), 0, stream,
                     xyzs, xyzt, w1, w2, bsrc, soff, stgt, w1at, w1bt, w2t);
  hipLaunchKernelGGL(nn_kernel, dim3(512), dim3(256), 0, stream, stgt, bsrc, soff, idxb, wgtb);
  hipLaunchKernelGGL(gemm_g, dim3(BS*NS/128, 2), dim3(256), 0, stream, fs, w1at, G);
  hipLaunchKernelGGL(fused_mlp, dim3(MTOT/32), dim3(256), 0, stream,
                     ft, G, idxb, wgtb, stgt, w1bt, w2t, (float*)d_out);
}